// Round 5
// baseline (2076.426 us; speedup 1.0000x reference)
//
#include <hip/hip_runtime.h>
#include <hip/hip_bf16.h>
#include <math.h>

// ---------------- types / helpers ----------------
typedef __attribute__((ext_vector_type(8))) __bf16 bf16x8;
typedef __attribute__((ext_vector_type(4))) float  f32x4;

__device__ __forceinline__ unsigned short f2bf(float f) {
    union { float f; unsigned int u; } x; x.f = f;
    unsigned int r = x.u + 0x7fffu + ((x.u >> 16) & 1u);   // RTNE
    return (unsigned short)(r >> 16);
}

// async global->LDS, 16B per lane; LDS dest = wave-uniform base + lane*16
__device__ __forceinline__ void gl_lds16(const unsigned short* g, unsigned short* l) {
    auto gp = (const unsigned int __attribute__((address_space(1)))*)((const void*)g);
    auto lp = (unsigned int __attribute__((address_space(3)))*)(unsigned int)(unsigned long long)((void*)l);
    __builtin_amdgcn_global_load_lds(gp, lp, 16, 0, 0);
}

#define B_   4
#define C_   512
#define T_   4096
#define NH   4
#define DH   128

// ---------------- weight converts (permute [co][ci][k] -> [co][k][ci], fp32->bf16) ----------------
__global__ __launch_bounds__(256) void cvt_wqkv(const float* __restrict__ w, unsigned short* __restrict__ o) {
    __shared__ unsigned short l[512 * 33];
    int co = blockIdx.x;
    const float* src = w + (size_t)co * 16384;
    for (int j = 0; j < 64; j++) {
        int i = threadIdx.x + j * 256;              // i = ci*32 + dk
        l[(i >> 5) * 33 + (i & 31)] = f2bf(src[i]);
    }
    __syncthreads();
    unsigned short* dst = o + (size_t)co * 16384;
    for (int j = 0; j < 64; j++) {
        int i = threadIdx.x + j * 256;              // i = dk*512 + ci
        int dk = i >> 9, ci = i & 511;
        dst[i] = l[ci * 33 + dk];
    }
}

__global__ __launch_bounds__(256) void cvt_wproj(const float* __restrict__ w, unsigned short* __restrict__ o) {
    __shared__ unsigned short l[512 * 6];
    int co = blockIdx.x;
    const float* src = w + (size_t)co * 2560;
    for (int j = 0; j < 10; j++) {
        int i = threadIdx.x + j * 256;              // i = ci*5 + dk
        int ci = i / 5, dk = i - ci * 5;
        l[ci * 6 + dk] = f2bf(src[i]);
    }
    __syncthreads();
    unsigned short* dst = o + (size_t)co * 2560;
    for (int j = 0; j < 10; j++) {
        int i = threadIdx.x + j * 256;              // i = dk*512 + ci
        int dk = i >> 9, ci = i & 511;
        dst[i] = l[ci * 6 + dk];
    }
}

// ---------------- GroupNorm -> bf16, single pass (x kept in registers), gnT[b][t][c] ----------------
__global__ __launch_bounds__(1024) void groupnorm(const float* __restrict__ x,
                                                  const float* __restrict__ gamma,
                                                  const float* __restrict__ beta,
                                                  unsigned short* __restrict__ gnT) {
    int g = blockIdx.x, b = blockIdx.y;
    int tid = threadIdx.x;
    const float* base = x + ((size_t)b * C_ + g * 16) * T_;
    const float4* b4 = (const float4*)base;
    float4 v[16];                                  // thread tid holds all 16 ch at t = tid*4..tid*4+3
    float s = 0.f, s2 = 0.f;
#pragma unroll
    for (int j = 0; j < 16; j++) {
        float4 w = b4[tid + j * 1024];
        v[j] = w;
        s  += w.x + w.y + w.z + w.w;
        s2 += w.x * w.x + w.y * w.y + w.z * w.z + w.w * w.w;
    }
    for (int off = 32; off; off >>= 1) { s += __shfl_down(s, off, 64); s2 += __shfl_down(s2, off, 64); }
    __shared__ float red[34];
    int wid = tid >> 6, lane = tid & 63;
    if (lane == 0) { red[wid] = s; red[16 + wid] = s2; }
    __syncthreads();
    if (tid == 0) {
        float ts = 0.f, ts2 = 0.f;
        for (int i = 0; i < 16; i++) { ts += red[i]; ts2 += red[16 + i]; }
        float mu = ts / 65536.f;
        float var = ts2 / 65536.f - mu * mu;
        red[32] = mu; red[33] = rsqrtf(var + 1e-5f);
    }
    __syncthreads();
    float mu = red[32], inv = red[33];
    float gm[16], bt[16];
#pragma unroll
    for (int cc = 0; cc < 16; cc++) { gm[cc] = gamma[g * 16 + cc] * inv; bt[cc] = beta[g * 16 + cc]; }
#pragma unroll
    for (int e = 0; e < 4; e++) {
        int t = tid * 4 + e;
        unsigned short outv[16];
#pragma unroll
        for (int cc = 0; cc < 16; cc++) {
            float xv = (e == 0) ? v[cc].x : (e == 1) ? v[cc].y : (e == 2) ? v[cc].z : v[cc].w;
            outv[cc] = f2bf((xv - mu) * gm[cc] + bt[cc]);
        }
        unsigned short* dst = gnT + ((size_t)b * T_ + t) * C_ + g * 16;
        *(uint4*)dst       = *(uint4*)outv;
        *(uint4*)(dst + 8) = *(uint4*)(outv + 8);
    }
}

// ---------------- QKV conv as GEMM: A(weights) in registers, B dbuf in LDS (32 KiB) ----------------
// grid.x = mblk (fastest: 12 co-resident blocks share B tile via L2), grid.y = (b<<5)|nblk
__global__ __launch_bounds__(256, 3) void gemm_qkv(const unsigned short* __restrict__ gnT,
                                                   const unsigned short* __restrict__ wq,   // [co][dk][ci] bf16
                                                   const float* __restrict__ bias,
                                                   unsigned short* __restrict__ qT,
                                                   unsigned short* __restrict__ kT,
                                                   unsigned short* __restrict__ vv) {
    int mblk = blockIdx.x;
    int nblk = blockIdx.y & 31, b = blockIdx.y >> 5;
    int m0 = mblk * 128, t0 = nblk * 128;
    __shared__ unsigned short Bs[2][128 * 64];   // [n=t][k], 16B block p of row r = src cols (p^(r&7))*8
    int tid = threadIdx.x, lane = tid & 63, wave = tid >> 6;
    int quad = lane >> 4, l16 = lane & 15;
    int wm = wave & 1, wn = wave >> 1;

    // B staging pointers
    int srow8 = lane >> 3, scb = (lane & 7) ^ srow8;
    const unsigned short* gb = gnT + (size_t)b * T_ * C_;
    const unsigned short* bp[4]; int lo[4];
#pragma unroll
    for (int i = 0; i < 4; i++) {
        int g = wave * 4 + i, row = g * 8 + srow8;
        bp[i] = gb + ((size_t)(t0 - 15 + row)) * 512 + scb * 8;   // halo over-read stays in ws
        lo[i] = g * 512;
    }
    // A row pointers (direct global->register)
    const unsigned short* ar[4];
#pragma unroll
    for (int mt = 0; mt < 4; mt++)
        ar[mt] = wq + (size_t)(m0 + wm * 64 + mt * 16 + l16) * 16384 + quad * 8;

    int fo[2];
#pragma unroll
    for (int kk = 0; kk < 2; kk++) fo[kk] = (((kk * 4 + quad) ^ (l16 & 7)) << 3);

    f32x4 acc[4][4];
    f32x4 z4 = {0.f, 0.f, 0.f, 0.f};
#pragma unroll
    for (int mt = 0; mt < 4; mt++)
#pragma unroll
        for (int nt = 0; nt < 4; nt++) acc[mt][nt] = z4;

    bool isF = (nblk == 0), isL = (nblk == 31);
    // prologue: stage B(0); load A frags for step 0
#pragma unroll
    for (int i = 0; i < 4; i++) gl_lds16(bp[i], &Bs[0][lo[i]]);
    bf16x8 af0[4], af1[4];
#pragma unroll
    for (int mt = 0; mt < 4; mt++) { af0[mt] = *(const bf16x8*)(ar[mt]); af1[mt] = *(const bf16x8*)(ar[mt] + 32); }

    for (int s = 0; s < 256; s++) {
        int cur = s & 1;
        __syncthreads();                          // drains stage(s) + A prefetch(s)
        int dk = s >> 3;
        if (isF && dk < 15) {                     // block-uniform edge path (2/32 blocks)
            int nz = 15 - dk, r = tid >> 3;
            if (r < nz) *(uint4*)&Bs[cur][(r << 6) + ((tid & 7) << 3)] = make_uint4(0, 0, 0, 0);
            __syncthreads();
        }
        if (isL && dk > 15) {
            int nb = dk - 15, rr = tid >> 3;
            if (rr < nb) *(uint4*)&Bs[cur][((128 - nb + rr) << 6) + ((tid & 7) << 3)] = make_uint4(0, 0, 0, 0);
            __syncthreads();
        }
        // stage B(s+1) into other buffer (completes during compute; drained at next barrier)
#pragma unroll
        for (int i = 0; i < 4; i++) gl_lds16(bp[i] + (s + 1) * 64, &Bs[cur ^ 1][lo[i]]);
        // kk = 0
        {
            bf16x8 b0[4];
#pragma unroll
            for (int nt = 0; nt < 4; nt++) b0[nt] = *(const bf16x8*)&Bs[cur][(wn * 64 + nt * 16 + l16) * 64 + fo[0]];
#pragma unroll
            for (int mt = 0; mt < 4; mt++)
#pragma unroll
                for (int nt = 0; nt < 4; nt++)
                    acc[mt][nt] = __builtin_amdgcn_mfma_f32_16x16x32_bf16(af0[mt], b0[nt], acc[mt][nt], 0, 0, 0);
        }
#pragma unroll
        for (int mt = 0; mt < 4; mt++) af0[mt] = *(const bf16x8*)(ar[mt] + (s + 1) * 64);      // prefetch A kk0(s+1)
        // kk = 1
        {
            bf16x8 b1[4];
#pragma unroll
            for (int nt = 0; nt < 4; nt++) b1[nt] = *(const bf16x8*)&Bs[cur][(wn * 64 + nt * 16 + l16) * 64 + fo[1]];
#pragma unroll
            for (int mt = 0; mt < 4; mt++)
#pragma unroll
                for (int nt = 0; nt < 4; nt++)
                    acc[mt][nt] = __builtin_amdgcn_mfma_f32_16x16x32_bf16(af1[mt], b1[nt], acc[mt][nt], 0, 0, 0);
        }
#pragma unroll
        for (int mt = 0; mt < 4; mt++) af1[mt] = *(const bf16x8*)(ar[mt] + (s + 1) * 64 + 32); // prefetch A kk1(s+1)
    }
    // epilogue: bias + bf16 + scatter to q/k/v layouts
#pragma unroll
    for (int mt = 0; mt < 4; mt++) {
        int cobase = m0 + wm * 64 + mt * 16 + quad * 4;
        int h = cobase / 384;
        int local = cobase - h * 384;
        int bh = b * NH + h;
#pragma unroll
        for (int nt = 0; nt < 4; nt++) {
            int t = t0 + wn * 64 + nt * 16 + l16;
            f32x4 a = acc[mt][nt];
            unsigned short r4[4];
            for (int r = 0; r < 4; r++) r4[r] = f2bf(a[r] + bias[cobase + r]);
            if (local < 128) {
                unsigned short* dst = qT + ((size_t)bh * T_ + t) * DH + local;
                *(uint2*)dst = *(uint2*)r4;
            } else if (local < 256) {
                unsigned short* dst = kT + ((size_t)bh * T_ + t) * DH + (local - 128);
                *(uint2*)dst = *(uint2*)r4;
            } else {
                unsigned short* dst = vv + ((size_t)bh * DH + (local - 256)) * T_ + t;
                for (int r = 0; r < 4; r++) dst[(size_t)r * T_] = r4[r];
            }
        }
    }
}

// ---------------- flash attention v3: 32 queries/wave (128/block), transposed scores ----------------
__global__ __launch_bounds__(256, 2) void attn(const unsigned short* __restrict__ qT,
                                               const unsigned short* __restrict__ kT,
                                               const unsigned short* __restrict__ vv,
                                               unsigned short* __restrict__ hT) {
    int q0 = blockIdx.x * 128, bh = blockIdx.y;
    int b = bh >> 2, h = bh & 3;
    __shared__ unsigned short Ks[64 * 128];   // [key][ch], swizzled
    __shared__ unsigned short Vs[128 * 64];   // [ch][key], swizzled
    __shared__ unsigned short Ps[128 * 72];   // [q][key], pad 72
    int tid = threadIdx.x, lane = tid & 63, wave = tid >> 6, quad = lane >> 4, l16 = lane & 15;

    bf16x8 bq[2][4];
#pragma unroll
    for (int u = 0; u < 2; u++) {
        const unsigned short* qrow = qT + ((size_t)bh * T_ + q0 + wave * 32 + u * 16 + l16) * DH + quad * 8;
#pragma unroll
        for (int kk = 0; kk < 4; kk++) bq[u][kk] = *(const bf16x8*)(qrow + kk * 32);
    }

    const unsigned short* kbase = kT + (size_t)bh * T_ * DH;
    const unsigned short* vbase = vv + (size_t)bh * DH * T_;
    int krow_in = lane >> 4, kp = lane & 15;
    int vrow_in = lane >> 3, vp = lane & 7;

    float m_i[2] = {-1e30f, -1e30f}, l_i[2] = {0.f, 0.f};
    f32x4 z4 = {0.f, 0.f, 0.f, 0.f};
    f32x4 o[2][8];
#pragma unroll
    for (int u = 0; u < 2; u++)
#pragma unroll
        for (int nt = 0; nt < 8; nt++) o[u][nt] = z4;
    const float scale2 = 0.08838834764831845f;    // 1/sqrt(128)

    for (int ts0 = 0; ts0 < T_; ts0 += 64) {
        __syncthreads();
#pragma unroll
        for (int i = 0; i < 4; i++) {
            int row = (wave * 4 + i) * 4 + krow_in;
            gl_lds16(kbase + ((size_t)(ts0 + row)) * DH + (((kp ^ (row & 7)) << 3)),
                     Ks + (wave * 4 + i) * 512);
        }
#pragma unroll
        for (int i = 0; i < 4; i++) {
            int row = (wave * 4 + i) * 8 + vrow_in;
            gl_lds16(vbase + (size_t)row * T_ + ts0 + (((vp ^ (row & 7)) << 3)),
                     Vs + (wave * 4 + i) * 512);
        }
        __syncthreads();

        f32x4 s[2][4];
#pragma unroll
        for (int u = 0; u < 2; u++)
#pragma unroll
            for (int mt = 0; mt < 4; mt++) s[u][mt] = z4;
#pragma unroll
        for (int kk = 0; kk < 4; kk++) {
            int pb = (((kk * 4 + quad) ^ (l16 & 7)) << 3);
#pragma unroll
            for (int mt = 0; mt < 4; mt++) {
                bf16x8 ak = *(const bf16x8*)&Ks[(mt * 16 + l16) * 128 + pb];
                s[0][mt] = __builtin_amdgcn_mfma_f32_16x16x32_bf16(ak, bq[0][kk], s[0][mt], 0, 0, 0);
                s[1][mt] = __builtin_amdgcn_mfma_f32_16x16x32_bf16(ak, bq[1][kk], s[1][mt], 0, 0, 0);
            }
        }
#pragma unroll
        for (int u = 0; u < 2; u++) {
            float mx = -1e30f;
#pragma unroll
            for (int mt = 0; mt < 4; mt++) {
                s[u][mt] *= scale2;
                mx = fmaxf(mx, fmaxf(fmaxf(s[u][mt][0], s[u][mt][1]), fmaxf(s[u][mt][2], s[u][mt][3])));
            }
            mx = fmaxf(mx, __shfl_xor(mx, 16, 64));
            mx = fmaxf(mx, __shfl_xor(mx, 32, 64));
            float mnew = fmaxf(m_i[u], mx);
            float alpha = __expf(m_i[u] - mnew);
            float rs = 0.f;
#pragma unroll
            for (int mt = 0; mt < 4; mt++) {
#pragma unroll
                for (int r = 0; r < 4; r++) { float p = __expf(s[u][mt][r] - mnew); s[u][mt][r] = p; rs += p; }
            }
            rs += __shfl_xor(rs, 16, 64);
            rs += __shfl_xor(rs, 32, 64);
            m_i[u] = mnew;
            l_i[u] = l_i[u] * alpha + rs;
#pragma unroll
            for (int mt = 0; mt < 4; mt++) {
                unsigned short t4[4];
#pragma unroll
                for (int r = 0; r < 4; r++) t4[r] = f2bf(s[u][mt][r]);
                *(uint2*)&Ps[(wave * 32 + u * 16 + l16) * 72 + mt * 16 + quad * 4] = *(uint2*)t4;
            }
            float a0 = __shfl(alpha, quad * 4 + 0, 64);
            float a1 = __shfl(alpha, quad * 4 + 1, 64);
            float a2 = __shfl(alpha, quad * 4 + 2, 64);
            float a3 = __shfl(alpha, quad * 4 + 3, 64);
            f32x4 av = {a0, a1, a2, a3};
#pragma unroll
            for (int nt = 0; nt < 8; nt++) o[u][nt] *= av;
        }
#pragma unroll
        for (int kk = 0; kk < 2; kk++) {
            int pb = (((kk * 4 + quad) ^ (l16 & 7)) << 3);
            bf16x8 ap0 = *(const bf16x8*)&Ps[(wave * 32 + l16) * 72 + kk * 32 + quad * 8];
            bf16x8 ap1 = *(const bf16x8*)&Ps[(wave * 32 + 16 + l16) * 72 + kk * 32 + quad * 8];
#pragma unroll
            for (int nt = 0; nt < 8; nt++) {
                bf16x8 bv = *(const bf16x8*)&Vs[(nt * 16 + l16) * 64 + pb];
                o[0][nt] = __builtin_amdgcn_mfma_f32_16x16x32_bf16(ap0, bv, o[0][nt], 0, 0, 0);
                o[1][nt] = __builtin_amdgcn_mfma_f32_16x16x32_bf16(ap1, bv, o[1][nt], 0, 0, 0);
            }
        }
    }
#pragma unroll
    for (int u = 0; u < 2; u++) {
        float i0 = 1.f / __shfl(l_i[u], quad * 4 + 0, 64);
        float i1 = 1.f / __shfl(l_i[u], quad * 4 + 1, 64);
        float i2 = 1.f / __shfl(l_i[u], quad * 4 + 2, 64);
        float i3 = 1.f / __shfl(l_i[u], quad * 4 + 3, 64);
        f32x4 iv = {i0, i1, i2, i3};
#pragma unroll
        for (int r = 0; r < 4; r++) {
            int t = q0 + wave * 32 + u * 16 + quad * 4 + r;
            unsigned short* dst = hT + ((size_t)b * T_ + t) * C_ + h * DH;
#pragma unroll
            for (int nt = 0; nt < 8; nt++) dst[nt * 16 + l16] = f2bf(o[u][nt][r] * iv[r]);
        }
    }
}

// ---------------- proj conv as GEMM (k=5): A in registers, B dbuf LDS ----------------
// grid.x = mblk(4), grid.y = (b<<5)|nblk
__global__ __launch_bounds__(256, 3) void gemm_proj(const unsigned short* __restrict__ hT,
                                                    const unsigned short* __restrict__ wp,   // [co][dk(5)][ci] bf16
                                                    const float* __restrict__ bias,
                                                    const float* __restrict__ x,
                                                    float* __restrict__ out) {
    int mblk = blockIdx.x;
    int nblk = blockIdx.y & 31, b = blockIdx.y >> 5;
    int m0 = mblk * 128, t0 = nblk * 128;
    __shared__ unsigned short Bs[2][128 * 64];
    int tid = threadIdx.x, lane = tid & 63, wave = tid >> 6;
    int quad = lane >> 4, l16 = lane & 15;
    int wm = wave & 1, wn = wave >> 1;

    int srow8 = lane >> 3, scb = (lane & 7) ^ srow8;
    const unsigned short* hb = hT + (size_t)b * T_ * C_;
    const unsigned short* bp[4]; int lo[4];
#pragma unroll
    for (int i = 0; i < 4; i++) {
        int g = wave * 4 + i, row = g * 8 + srow8;
        bp[i] = hb + ((size_t)(t0 - 2 + row)) * 512 + scb * 8;
        lo[i] = g * 512;
    }
    const unsigned short* ar[4];
#pragma unroll
    for (int mt = 0; mt < 4; mt++)
        ar[mt] = wp + (size_t)(m0 + wm * 64 + mt * 16 + l16) * 2560 + quad * 8;

    int fo[2];
#pragma unroll
    for (int kk = 0; kk < 2; kk++) fo[kk] = (((kk * 4 + quad) ^ (l16 & 7)) << 3);

    f32x4 acc[4][4];
    f32x4 z4 = {0.f, 0.f, 0.f, 0.f};
#pragma unroll
    for (int mt = 0; mt < 4; mt++)
#pragma unroll
        for (int nt = 0; nt < 4; nt++) acc[mt][nt] = z4;

    bool isF = (nblk == 0), isL = (nblk == 31);
#pragma unroll
    for (int i = 0; i < 4; i++) gl_lds16(bp[i], &Bs[0][lo[i]]);
    bf16x8 af0[4], af1[4];
#pragma unroll
    for (int mt = 0; mt < 4; mt++) { af0[mt] = *(const bf16x8*)(ar[mt]); af1[mt] = *(const bf16x8*)(ar[mt] + 32); }

    for (int s = 0; s < 40; s++) {
        int cur = s & 1;
        __syncthreads();
        int dk = s >> 3;
        if (isF && dk < 2) {
            int nz = 2 - dk, r = tid >> 3;
            if (r < nz) *(uint4*)&Bs[cur][(r << 6) + ((tid & 7) << 3)] = make_uint4(0, 0, 0, 0);
            __syncthreads();
        }
        if (isL && dk > 2) {
            int nb = dk - 2, rr = tid >> 3;
            if (rr < nb) *(uint4*)&Bs[cur][((128 - nb + rr) << 6) + ((tid & 7) << 3)] = make_uint4(0, 0, 0, 0);
            __syncthreads();
        }
#pragma unroll
        for (int i = 0; i < 4; i++) gl_lds16(bp[i] + (s + 1) * 64, &Bs[cur ^ 1][lo[i]]);
        {
            bf16x8 b0[4];
#pragma unroll
            for (int nt = 0; nt < 4; nt++) b0[nt] = *(const bf16x8*)&Bs[cur][(wn * 64 + nt * 16 + l16) * 64 + fo[0]];
#pragma unroll
            for (int mt = 0; mt < 4; mt++)
#pragma unroll
                for (int nt = 0; nt < 4; nt++)
                    acc[mt][nt] = __builtin_amdgcn_mfma_f32_16x16x32_bf16(af0[mt], b0[nt], acc[mt][nt], 0, 0, 0);
        }
#pragma unroll
        for (int mt = 0; mt < 4; mt++) af0[mt] = *(const bf16x8*)(ar[mt] + (s + 1) * 64);
        {
            bf16x8 b1[4];
#pragma unroll
            for (int nt = 0; nt < 4; nt++) b1[nt] = *(const bf16x8*)&Bs[cur][(wn * 64 + nt * 16 + l16) * 64 + fo[1]];
#pragma unroll
            for (int mt = 0; mt < 4; mt++)
#pragma unroll
                for (int nt = 0; nt < 4; nt++)
                    acc[mt][nt] = __builtin_amdgcn_mfma_f32_16x16x32_bf16(af1[mt], b1[nt], acc[mt][nt], 0, 0, 0);
        }
#pragma unroll
        for (int mt = 0; mt < 4; mt++) af1[mt] = *(const bf16x8*)(ar[mt] + (s + 1) * 64 + 32);
    }
#pragma unroll
    for (int mt = 0; mt < 4; mt++) {
        int cobase = m0 + wm * 64 + mt * 16 + quad * 4;
#pragma unroll
        for (int nt = 0; nt < 4; nt++) {
            int t = t0 + wn * 64 + nt * 16 + l16;
            for (int r = 0; r < 4; r++) {
                int co = cobase + r;
                size_t idx = ((size_t)(b * C_ + co)) * T_ + t;
                out[idx] = acc[mt][nt][r] + bias[co] + x[idx];
            }
        }
    }
}

// ---------------- launch ----------------
extern "C" void kernel_launch(void* const* d_in, const int* in_sizes, int n_in,
                              void* d_out, int out_size, void* d_ws, size_t ws_size,
                              hipStream_t stream) {
    const float* x      = (const float*)d_in[0];
    const float* gamma  = (const float*)d_in[1];
    const float* beta   = (const float*)d_in[2];
    const float* qkv_w  = (const float*)d_in[3];
    const float* qkv_b  = (const float*)d_in[4];
    const float* proj_w = (const float*)d_in[5];
    const float* proj_b = (const float*)d_in[6];
    float* out = (float*)d_out;
    char* ws = (char*)d_ws;

    // gnT/hT sits between wprojT and qTb so halo over-reads stay inside ws.
    unsigned short* wqkvT  = (unsigned short*)(ws);               // 48 MiB  [1536][32][512]
    unsigned short* wprojT = (unsigned short*)(ws + 50331648);    // 2.5 MiB [512][5][512]
    unsigned short* gnT    = (unsigned short*)(ws + 52953088);    // 16 MiB  [4][4096][512]
    unsigned short* qTb    = (unsigned short*)(ws + 69730304);    // 16 MiB  [16][4096][128]
    unsigned short* kTb    = (unsigned short*)(ws + 86507520);    // 16 MiB
    unsigned short* vb     = (unsigned short*)(ws + 103284736);   // 16 MiB  [16][128][4096]
    unsigned short* hT     = gnT;  // reuse: gnT dead after gemm_qkv

    hipLaunchKernelGGL(cvt_wqkv,  dim3(1536),    dim3(256),  0, stream, qkv_w, wqkvT);
    hipLaunchKernelGGL(cvt_wproj, dim3(512),     dim3(256),  0, stream, proj_w, wprojT);
    hipLaunchKernelGGL(groupnorm, dim3(32, 4),   dim3(1024), 0, stream, x, gamma, beta, gnT);
    hipLaunchKernelGGL(gemm_qkv,  dim3(12, 128), dim3(256),  0, stream, gnT, wqkvT, qkv_b, qTb, kTb, vb);
    hipLaunchKernelGGL(attn,      dim3(32, 16),  dim3(256),  0, stream, qTb, kTb, vb, hT);
    hipLaunchKernelGGL(gemm_proj, dim3(4, 128),  dim3(256),  0, stream, hT, wprojT, proj_b, x, out);
}

// Round 6
// 1016.306 us; speedup vs baseline: 2.0431x; 2.0431x over previous
//
#include <hip/hip_runtime.h>
#include <hip/hip_bf16.h>
#include <math.h>

// ---------------- types / helpers ----------------
typedef __attribute__((ext_vector_type(8))) __bf16 bf16x8;
typedef __attribute__((ext_vector_type(4))) float  f32x4;

__device__ __forceinline__ unsigned short f2bf(float f) {
    union { float f; unsigned int u; } x; x.f = f;
    unsigned int r = x.u + 0x7fffu + ((x.u >> 16) & 1u);   // RTNE
    return (unsigned short)(r >> 16);
}

// async global->LDS, 16B per lane; LDS dest = wave-uniform base + lane*16
__device__ __forceinline__ void gl_lds16(const unsigned short* g, unsigned short* l) {
    auto gp = (const unsigned int __attribute__((address_space(1)))*)((const void*)g);
    auto lp = (unsigned int __attribute__((address_space(3)))*)(unsigned int)(unsigned long long)((void*)l);
    __builtin_amdgcn_global_load_lds(gp, lp, 16, 0, 0);
}

#define B_   4
#define C_   512
#define T_   4096
#define NH   4
#define DH   128

// ---------------- weight converts (permute [co][ci][k] -> [co][k][ci], fp32->bf16) ----------------
__global__ __launch_bounds__(256) void cvt_wqkv(const float* __restrict__ w, unsigned short* __restrict__ o) {
    __shared__ unsigned short l[512 * 33];
    int co = blockIdx.x;
    const float* src = w + (size_t)co * 16384;
    for (int j = 0; j < 64; j++) {
        int i = threadIdx.x + j * 256;              // i = ci*32 + dk
        l[(i >> 5) * 33 + (i & 31)] = f2bf(src[i]);
    }
    __syncthreads();
    unsigned short* dst = o + (size_t)co * 16384;
    for (int j = 0; j < 64; j++) {
        int i = threadIdx.x + j * 256;              // i = dk*512 + ci
        int dk = i >> 9, ci = i & 511;
        dst[i] = l[ci * 33 + dk];
    }
}

__global__ __launch_bounds__(256) void cvt_wproj(const float* __restrict__ w, unsigned short* __restrict__ o) {
    __shared__ unsigned short l[512 * 6];
    int co = blockIdx.x;
    const float* src = w + (size_t)co * 2560;
    for (int j = 0; j < 10; j++) {
        int i = threadIdx.x + j * 256;              // i = ci*5 + dk
        int ci = i / 5, dk = i - ci * 5;
        l[ci * 6 + dk] = f2bf(src[i]);
    }
    __syncthreads();
    unsigned short* dst = o + (size_t)co * 2560;
    for (int j = 0; j < 10; j++) {
        int i = threadIdx.x + j * 256;              // i = dk*512 + ci
        int dk = i >> 9, ci = i & 511;
        dst[i] = l[ci * 6 + dk];
    }
}

// ---------------- GroupNorm -> bf16, single pass (x kept in registers), gnT[b][t][c] ----------------
__global__ __launch_bounds__(1024) void groupnorm(const float* __restrict__ x,
                                                  const float* __restrict__ gamma,
                                                  const float* __restrict__ beta,
                                                  unsigned short* __restrict__ gnT) {
    int g = blockIdx.x, b = blockIdx.y;
    int tid = threadIdx.x;
    const float* base = x + ((size_t)b * C_ + g * 16) * T_;
    const float4* b4 = (const float4*)base;
    float4 v[16];
    float s = 0.f, s2 = 0.f;
#pragma unroll
    for (int j = 0; j < 16; j++) {
        float4 w = b4[tid + j * 1024];
        v[j] = w;
        s  += w.x + w.y + w.z + w.w;
        s2 += w.x * w.x + w.y * w.y + w.z * w.z + w.w * w.w;
    }
    for (int off = 32; off; off >>= 1) { s += __shfl_down(s, off, 64); s2 += __shfl_down(s2, off, 64); }
    __shared__ float red[34];
    int wid = tid >> 6, lane = tid & 63;
    if (lane == 0) { red[wid] = s; red[16 + wid] = s2; }
    __syncthreads();
    if (tid == 0) {
        float ts = 0.f, ts2 = 0.f;
        for (int i = 0; i < 16; i++) { ts += red[i]; ts2 += red[16 + i]; }
        float mu = ts / 65536.f;
        float var = ts2 / 65536.f - mu * mu;
        red[32] = mu; red[33] = rsqrtf(var + 1e-5f);
    }
    __syncthreads();
    float mu = red[32], inv = red[33];
    float gm[16], bt[16];
#pragma unroll
    for (int cc = 0; cc < 16; cc++) { gm[cc] = gamma[g * 16 + cc] * inv; bt[cc] = beta[g * 16 + cc]; }
#pragma unroll
    for (int e = 0; e < 4; e++) {
        int t = tid * 4 + e;
        unsigned short outv[16];
#pragma unroll
        for (int cc = 0; cc < 16; cc++) {
            float xv = (e == 0) ? v[cc].x : (e == 1) ? v[cc].y : (e == 2) ? v[cc].z : v[cc].w;
            outv[cc] = f2bf((xv - mu) * gm[cc] + bt[cc]);
        }
        unsigned short* dst = gnT + ((size_t)b * T_ + t) * C_ + g * 16;
        *(uint4*)dst       = *(uint4*)outv;
        *(uint4*)(dst + 8) = *(uint4*)(outv + 8);
    }
}

// ---------------- QKV conv as GEMM v6: B-slab (conv reuse) + 64x128 wave tiles ----------------
// block = 128 co x 256 t; waves 2x2, wave tile 64 x 128. K = ci-chunk(8 x 64) x dk(32).
// B slab: 288 rows x 64 ci staged once per ci-chunk (kills per-step B staging).
// A: 128x64 tile per dk, double-buffered LDS.
// grid.x = b(4) * nblk(16) [fast], grid.y = mblk(12)
__global__ __launch_bounds__(256, 2) void gemm_qkv(const unsigned short* __restrict__ gnT,
                                                   const unsigned short* __restrict__ wq,   // [co][dk*512+ci] bf16
                                                   const float* __restrict__ bias,
                                                   unsigned short* __restrict__ qT,
                                                   unsigned short* __restrict__ kT,
                                                   unsigned short* __restrict__ vv) {
    int b = blockIdx.x & 3, nblk = blockIdx.x >> 2, mblk = blockIdx.y;
    int m0 = mblk * 128, t0 = nblk * 256;
    __shared__ unsigned short As[2][128 * 64];   // [co][k64], block p of row r holds src block p^(r&7)
    __shared__ unsigned short Bsl[288 * 64];     // [t-row][ci64], same swizzle
    int tid = threadIdx.x, lane = tid & 63, wave = tid >> 6;
    int quad = lane >> 4, l16 = lane & 15;
    int wm = wave & 1, wn = wave >> 1;

    const unsigned short* gb = gnT + (size_t)b * T_ * C_;
    int srow = tid >> 3, spc = tid & 7;          // staging: 8 lanes per 128B row

    int fo[2];                                   // A frag block offsets (row&7 == l16&7)
    fo[0] = ((quad ^ (l16 & 7)) << 3);
    fo[1] = (((4 + quad) ^ (l16 & 7)) << 3);
    int rowb = wn * 128 + l16;                   // B frag base row (pre-dk)

    f32x4 acc[4][8];
    f32x4 z4 = {0.f, 0.f, 0.f, 0.f};
#pragma unroll
    for (int mt = 0; mt < 4; mt++)
#pragma unroll
        for (int nt = 0; nt < 8; nt++) acc[mt][nt] = z4;

    bool isF = (nblk == 0), isL = (nblk == 15);

    for (int cc = 0; cc < 8; cc++) {
        // stage B slab: 288 rows x 64 ci (halo t0-15 .. t0+272); over-reads stay inside ws
#pragma unroll
        for (int i = 0; i < 9; i++) {
            int row = i * 32 + srow;
            int p = spc ^ (row & 7);
            gl_lds16(gb + (size_t)(t0 - 15 + row) * 512 + cc * 64 + p * 8,
                     Bsl + (i * 256 + wave * 64) * 8);
        }
        // stage A(dk=0)
#pragma unroll
        for (int i = 0; i < 4; i++) {
            int row = i * 32 + srow;
            int p = spc ^ (row & 7);
            gl_lds16(wq + (size_t)(m0 + row) * 16384 + cc * 64 + p * 8,
                     As[0] + (i * 256 + wave * 64) * 8);
        }
        __syncthreads();
        if (isF) {                                // zero slab rows with t < 0
            if (tid < 15 * 8) *(uint4*)&Bsl[(tid >> 3) * 64 + (tid & 7) * 8] = make_uint4(0, 0, 0, 0);
            __syncthreads();
        }
        if (isL) {                                // zero slab rows with t >= 4096 (rows 271..287)
            if (tid < 17 * 8) *(uint4*)&Bsl[(271 + (tid >> 3)) * 64 + (tid & 7) * 8] = make_uint4(0, 0, 0, 0);
            __syncthreads();
        }
        for (int dk = 0; dk < 32; dk++) {
            int cur = dk & 1;
            if (dk != 31) {                       // prefetch A(dk+1); drained at end-of-iter barrier
#pragma unroll
                for (int i = 0; i < 4; i++) {
                    int row = i * 32 + srow;
                    int p = spc ^ (row & 7);
                    gl_lds16(wq + (size_t)(m0 + row) * 16384 + (dk + 1) * 512 + cc * 64 + p * 8,
                             As[cur ^ 1] + (i * 256 + wave * 64) * 8);
                }
            }
            int rd = rowb + dk;
            int pb0 = ((quad ^ (rd & 7)) << 3);
            int pb1 = (((4 + quad) ^ (rd & 7)) << 3);
#pragma unroll
            for (int kk = 0; kk < 2; kk++) {
                int pbk = kk ? pb1 : pb0;
                bf16x8 af[4], bfr[8];
#pragma unroll
                for (int mt = 0; mt < 4; mt++)
                    af[mt] = *(const bf16x8*)&As[cur][(wm * 64 + mt * 16 + l16) * 64 + fo[kk]];
#pragma unroll
                for (int nt = 0; nt < 8; nt++)
                    bfr[nt] = *(const bf16x8*)&Bsl[(rd + nt * 16) * 64 + pbk];
#pragma unroll
                for (int mt = 0; mt < 4; mt++)
#pragma unroll
                    for (int nt = 0; nt < 8; nt++)
                        acc[mt][nt] = __builtin_amdgcn_mfma_f32_16x16x32_bf16(af[mt], bfr[nt], acc[mt][nt], 0, 0, 0);
            }
            __syncthreads();
        }
    }
    // epilogue: bias + bf16 + scatter to q/k/v layouts
#pragma unroll
    for (int mt = 0; mt < 4; mt++) {
        int cobase = m0 + wm * 64 + mt * 16 + quad * 4;
        int h = cobase / 384;
        int local = cobase - h * 384;
        int bh = b * NH + h;
#pragma unroll
        for (int nt = 0; nt < 8; nt++) {
            int t = t0 + wn * 128 + nt * 16 + l16;
            f32x4 a = acc[mt][nt];
            unsigned short r4[4];
            for (int r = 0; r < 4; r++) r4[r] = f2bf(a[r] + bias[cobase + r]);
            if (local < 128) {
                unsigned short* dst = qT + ((size_t)bh * T_ + t) * DH + local;
                *(uint2*)dst = *(uint2*)r4;
            } else if (local < 256) {
                unsigned short* dst = kT + ((size_t)bh * T_ + t) * DH + (local - 128);
                *(uint2*)dst = *(uint2*)r4;
            } else {
                unsigned short* dst = vv + ((size_t)bh * DH + (local - 256)) * T_ + t;
                for (int r = 0; r < 4; r++) dst[(size_t)r * T_] = r4[r];
            }
        }
    }
}

// ---------------- flash attention v3: 32 queries/wave (128/block), transposed scores ----------------
__global__ __launch_bounds__(256, 2) void attn(const unsigned short* __restrict__ qT,
                                               const unsigned short* __restrict__ kT,
                                               const unsigned short* __restrict__ vv,
                                               unsigned short* __restrict__ hT) {
    int q0 = blockIdx.x * 128, bh = blockIdx.y;
    int b = bh >> 2, h = bh & 3;
    __shared__ unsigned short Ks[64 * 128];
    __shared__ unsigned short Vs[128 * 64];
    __shared__ unsigned short Ps[128 * 72];
    int tid = threadIdx.x, lane = tid & 63, wave = tid >> 6, quad = lane >> 4, l16 = lane & 15;

    bf16x8 bq[2][4];
#pragma unroll
    for (int u = 0; u < 2; u++) {
        const unsigned short* qrow = qT + ((size_t)bh * T_ + q0 + wave * 32 + u * 16 + l16) * DH + quad * 8;
#pragma unroll
        for (int kk = 0; kk < 4; kk++) bq[u][kk] = *(const bf16x8*)(qrow + kk * 32);
    }

    const unsigned short* kbase = kT + (size_t)bh * T_ * DH;
    const unsigned short* vbase = vv + (size_t)bh * DH * T_;
    int krow_in = lane >> 4, kp = lane & 15;
    int vrow_in = lane >> 3, vp = lane & 7;

    float m_i[2] = {-1e30f, -1e30f}, l_i[2] = {0.f, 0.f};
    f32x4 z4 = {0.f, 0.f, 0.f, 0.f};
    f32x4 o[2][8];
#pragma unroll
    for (int u = 0; u < 2; u++)
#pragma unroll
        for (int nt = 0; nt < 8; nt++) o[u][nt] = z4;
    const float scale2 = 0.08838834764831845f;

    for (int ts0 = 0; ts0 < T_; ts0 += 64) {
        __syncthreads();
#pragma unroll
        for (int i = 0; i < 4; i++) {
            int row = (wave * 4 + i) * 4 + krow_in;
            gl_lds16(kbase + ((size_t)(ts0 + row)) * DH + (((kp ^ (row & 7)) << 3)),
                     Ks + (wave * 4 + i) * 512);
        }
#pragma unroll
        for (int i = 0; i < 4; i++) {
            int row = (wave * 4 + i) * 8 + vrow_in;
            gl_lds16(vbase + (size_t)row * T_ + ts0 + (((vp ^ (row & 7)) << 3)),
                     Vs + (wave * 4 + i) * 512);
        }
        __syncthreads();

        f32x4 s[2][4];
#pragma unroll
        for (int u = 0; u < 2; u++)
#pragma unroll
            for (int mt = 0; mt < 4; mt++) s[u][mt] = z4;
#pragma unroll
        for (int kk = 0; kk < 4; kk++) {
            int pb = (((kk * 4 + quad) ^ (l16 & 7)) << 3);
#pragma unroll
            for (int mt = 0; mt < 4; mt++) {
                bf16x8 ak = *(const bf16x8*)&Ks[(mt * 16 + l16) * 128 + pb];
                s[0][mt] = __builtin_amdgcn_mfma_f32_16x16x32_bf16(ak, bq[0][kk], s[0][mt], 0, 0, 0);
                s[1][mt] = __builtin_amdgcn_mfma_f32_16x16x32_bf16(ak, bq[1][kk], s[1][mt], 0, 0, 0);
            }
        }
#pragma unroll
        for (int u = 0; u < 2; u++) {
            float mx = -1e30f;
#pragma unroll
            for (int mt = 0; mt < 4; mt++) {
                s[u][mt] *= scale2;
                mx = fmaxf(mx, fmaxf(fmaxf(s[u][mt][0], s[u][mt][1]), fmaxf(s[u][mt][2], s[u][mt][3])));
            }
            mx = fmaxf(mx, __shfl_xor(mx, 16, 64));
            mx = fmaxf(mx, __shfl_xor(mx, 32, 64));
            float mnew = fmaxf(m_i[u], mx);
            float alpha = __expf(m_i[u] - mnew);
            float rs = 0.f;
#pragma unroll
            for (int mt = 0; mt < 4; mt++) {
#pragma unroll
                for (int r = 0; r < 4; r++) { float p = __expf(s[u][mt][r] - mnew); s[u][mt][r] = p; rs += p; }
            }
            rs += __shfl_xor(rs, 16, 64);
            rs += __shfl_xor(rs, 32, 64);
            m_i[u] = mnew;
            l_i[u] = l_i[u] * alpha + rs;
#pragma unroll
            for (int mt = 0; mt < 4; mt++) {
                unsigned short t4[4];
#pragma unroll
                for (int r = 0; r < 4; r++) t4[r] = f2bf(s[u][mt][r]);
                *(uint2*)&Ps[(wave * 32 + u * 16 + l16) * 72 + mt * 16 + quad * 4] = *(uint2*)t4;
            }
            float a0 = __shfl(alpha, quad * 4 + 0, 64);
            float a1 = __shfl(alpha, quad * 4 + 1, 64);
            float a2 = __shfl(alpha, quad * 4 + 2, 64);
            float a3 = __shfl(alpha, quad * 4 + 3, 64);
            f32x4 av = {a0, a1, a2, a3};
#pragma unroll
            for (int nt = 0; nt < 8; nt++) o[u][nt] *= av;
        }
#pragma unroll
        for (int kk = 0; kk < 2; kk++) {
            int pb = (((kk * 4 + quad) ^ (l16 & 7)) << 3);
            bf16x8 ap0 = *(const bf16x8*)&Ps[(wave * 32 + l16) * 72 + kk * 32 + quad * 8];
            bf16x8 ap1 = *(const bf16x8*)&Ps[(wave * 32 + 16 + l16) * 72 + kk * 32 + quad * 8];
#pragma unroll
            for (int nt = 0; nt < 8; nt++) {
                bf16x8 bv = *(const bf16x8*)&Vs[(nt * 16 + l16) * 64 + pb];
                o[0][nt] = __builtin_amdgcn_mfma_f32_16x16x32_bf16(ap0, bv, o[0][nt], 0, 0, 0);
                o[1][nt] = __builtin_amdgcn_mfma_f32_16x16x32_bf16(ap1, bv, o[1][nt], 0, 0, 0);
            }
        }
    }
#pragma unroll
    for (int u = 0; u < 2; u++) {
        float i0 = 1.f / __shfl(l_i[u], quad * 4 + 0, 64);
        float i1 = 1.f / __shfl(l_i[u], quad * 4 + 1, 64);
        float i2 = 1.f / __shfl(l_i[u], quad * 4 + 2, 64);
        float i3 = 1.f / __shfl(l_i[u], quad * 4 + 3, 64);
        f32x4 iv = {i0, i1, i2, i3};
#pragma unroll
        for (int r = 0; r < 4; r++) {
            int t = q0 + wave * 32 + u * 16 + quad * 4 + r;
            unsigned short* dst = hT + ((size_t)b * T_ + t) * C_ + h * DH;
#pragma unroll
            for (int nt = 0; nt < 8; nt++) dst[nt * 16 + l16] = f2bf(o[u][nt][r] * iv[r]);
        }
    }
}

// ---------------- proj conv as GEMM (k=5), BK=64, r3 structure (proven) ----------------
__global__ __launch_bounds__(256, 3) void gemm_proj(const unsigned short* __restrict__ hT,
                                                    const unsigned short* __restrict__ wp,   // [co][dk(5)][ci] bf16
                                                    const float* __restrict__ bias,
                                                    const float* __restrict__ x,
                                                    float* __restrict__ out) {
    int nblk = blockIdx.x, mblk = blockIdx.y, b = blockIdx.z;
    int m0 = mblk * 128, t0 = nblk * 128;
    __shared__ unsigned short As[128 * 64], Bs[128 * 64];
    int tid = threadIdx.x, lane = tid & 63, wave = tid >> 6;
    int quad = lane >> 4, l16 = lane & 15;
    int wm = wave & 1, wn = wave >> 1;

    int srow8 = lane >> 3;
    int scb = (lane & 7) ^ srow8;
    const unsigned short* hb = hT + (size_t)b * T_ * C_;
    const unsigned short* ap[4]; const unsigned short* bp[4];
    unsigned short *la[4], *lb[4];
#pragma unroll
    for (int i = 0; i < 4; i++) {
        int g = wave * 4 + i;
        int row = g * 8 + srow8;
        ap[i] = wp + (size_t)(m0 + row) * 2560 + scb * 8;
        bp[i] = hb + ((size_t)(t0 - 2 + row)) * 512 + scb * 8;
        la[i] = As + g * 512;
        lb[i] = Bs + g * 512;
    }
    const unsigned short* pAr[2]; const unsigned short* pBr[2];
#pragma unroll
    for (int kk = 0; kk < 2; kk++) {
        pAr[kk] = As + (wm * 64 + l16) * 64 + (((kk * 4 + quad) ^ (l16 & 7)) << 3);
        pBr[kk] = Bs + (wn * 64 + l16) * 64 + (((kk * 4 + quad) ^ (l16 & 7)) << 3);
    }
    f32x4 acc[4][4];
    f32x4 z4 = {0.f, 0.f, 0.f, 0.f};
#pragma unroll
    for (int mt = 0; mt < 4; mt++)
#pragma unroll
        for (int nt = 0; nt < 4; nt++) acc[mt][nt] = z4;

    bool isF = (nblk == 0), isL = (nblk == 31);
    for (int s = 0; s < 40; s++) {
        __syncthreads();
#pragma unroll
        for (int i = 0; i < 4; i++) { gl_lds16(ap[i], la[i]); ap[i] += 64; }
#pragma unroll
        for (int i = 0; i < 4; i++) { gl_lds16(bp[i], lb[i]); bp[i] += 64; }
        __syncthreads();
        int dk = s >> 3;
        if (isF && dk < 2) {
            int nz = 2 - dk, r = tid >> 3;
            if (r < nz) *(uint4*)&Bs[(r << 6) + ((tid & 7) << 3)] = make_uint4(0, 0, 0, 0);
            __syncthreads();
        }
        if (isL && dk > 2) {
            int nb = dk - 2, rr = tid >> 3;
            if (rr < nb) *(uint4*)&Bs[((128 - nb + rr) << 6) + ((tid & 7) << 3)] = make_uint4(0, 0, 0, 0);
            __syncthreads();
        }
#pragma unroll
        for (int kk = 0; kk < 2; kk++) {
            bf16x8 af[4], bfr[4];
#pragma unroll
            for (int mt = 0; mt < 4; mt++) af[mt]  = *(const bf16x8*)(pAr[kk] + mt * 1024);
#pragma unroll
            for (int nt = 0; nt < 4; nt++) bfr[nt] = *(const bf16x8*)(pBr[kk] + nt * 1024);
#pragma unroll
            for (int mt = 0; mt < 4; mt++)
#pragma unroll
                for (int nt = 0; nt < 4; nt++)
                    acc[mt][nt] = __builtin_amdgcn_mfma_f32_16x16x32_bf16(af[mt], bfr[nt], acc[mt][nt], 0, 0, 0);
        }
    }
#pragma unroll
    for (int mt = 0; mt < 4; mt++) {
        int cobase = m0 + wm * 64 + mt * 16 + quad * 4;
#pragma unroll
        for (int nt = 0; nt < 4; nt++) {
            int t = t0 + wn * 64 + nt * 16 + l16;
            for (int r = 0; r < 4; r++) {
                int co = cobase + r;
                size_t idx = ((size_t)(b * C_ + co)) * T_ + t;
                out[idx] = acc[mt][nt][r] + bias[co] + x[idx];
            }
        }
    }
}

// ---------------- launch ----------------
extern "C" void kernel_launch(void* const* d_in, const int* in_sizes, int n_in,
                              void* d_out, int out_size, void* d_ws, size_t ws_size,
                              hipStream_t stream) {
    const float* x      = (const float*)d_in[0];
    const float* gamma  = (const float*)d_in[1];
    const float* beta   = (const float*)d_in[2];
    const float* qkv_w  = (const float*)d_in[3];
    const float* qkv_b  = (const float*)d_in[4];
    const float* proj_w = (const float*)d_in[5];
    const float* proj_b = (const float*)d_in[6];
    float* out = (float*)d_out;
    char* ws = (char*)d_ws;

    // gnT/hT sits between wprojT and qTb so halo over-reads stay inside ws.
    unsigned short* wqkvT  = (unsigned short*)(ws);               // 48 MiB  [1536][32][512]
    unsigned short* wprojT = (unsigned short*)(ws + 50331648);    // 2.5 MiB [512][5][512]
    unsigned short* gnT    = (unsigned short*)(ws + 52953088);    // 16 MiB  [4][4096][512]
    unsigned short* qTb    = (unsigned short*)(ws + 69730304);    // 16 MiB  [16][4096][128]
    unsigned short* kTb    = (unsigned short*)(ws + 86507520);    // 16 MiB
    unsigned short* vb     = (unsigned short*)(ws + 103284736);   // 16 MiB  [16][128][4096]
    unsigned short* hT     = gnT;  // reuse: gnT dead after gemm_qkv

    hipLaunchKernelGGL(cvt_wqkv,  dim3(1536),     dim3(256),  0, stream, qkv_w, wqkvT);
    hipLaunchKernelGGL(cvt_wproj, dim3(512),      dim3(256),  0, stream, proj_w, wprojT);
    hipLaunchKernelGGL(groupnorm, dim3(32, 4),    dim3(1024), 0, stream, x, gamma, beta, gnT);
    hipLaunchKernelGGL(gemm_qkv,  dim3(64, 12),   dim3(256),  0, stream, gnT, wqkvT, qkv_b, qTb, kTb, vb);
    hipLaunchKernelGGL(attn,      dim3(32, 16),   dim3(256),  0, stream, qTb, kTb, vb, hT);
    hipLaunchKernelGGL(gemm_proj, dim3(32, 4, 4), dim3(256),  0, stream, hT, wprojT, proj_b, x, out);
}